// Round 5
// baseline (353.585 us; speedup 1.0000x reference)
//
#include <hip/hip_runtime.h>
#include <stdint.h>

static constexpr int HIN = 256, WIN = 256, HO = 254, WOUT = 254, NB = 8;
static constexpr int PLANE = HO * WOUT;       // 64516
static constexpr int PIX = NB * PLANE;        // 516128

// Per-level atom counts N = {8,16,32,64}, K = {2,4,8,16}, ch0 = {0,8,24,56}.
// Unified tables padded to 64 atoms/level (zeros beyond N): one rolled level
// loop => the whole kernel body is emitted ONCE (~15 KB) and stays I-cache
// resident. Padded atoms compute exactly 0.0f and are never stored.
__device__ float g_wPad[4 * 27 * 64];
__device__ float g_bPad[4 * 64];

__constant__ int cN[4]   = {8, 16, 32, 64};
__constant__ int cK[4]   = {2, 4, 8, 16};
__constant__ int cCH0[4] = {0, 8, 24, 56};

// g_wPad[L][s][j] = w[(ch0_L+j)*27 + t(s)] for j<N_L else 0, where step
// s = ky*9+kx*3+c enumerates the VALIDATED (ky,kx,c) FMA order and
// t(s) = c*9+ky*3+kx is the source (c,ky,kx) layout offset.
__global__ void wprep(const float* __restrict__ w, const float* __restrict__ b) {
  int i = blockIdx.x * blockDim.x + threadIdx.x;
  if (i < 4 * 64) {
    int L = i / 64, j = i % 64;
    int N = 8 << L;
    int ch0 = (L == 0) ? 0 : (L == 1) ? 8 : (L == 2) ? 24 : 56;
    g_bPad[i] = (j < N) ? b[ch0 + j] : 0.0f;
  }
  if (i >= 4 * 27 * 64) return;
  int L = i / (27 * 64), r = i % (27 * 64), s = r / 64, j = r % 64;
  int N = 8 << L;
  int ch0 = (L == 0) ? 0 : (L == 1) ? 8 : (L == 2) ? 24 : 56;
  int ky = s / 9, kx = (s / 3) % 3, c = s % 3;
  g_wPad[i] = (j < N) ? w[(size_t)(ch0 + j) * 27 + c * 9 + ky * 3 + kx] : 0.0f;
}

// Ring connectivity: prev atom j feeds next atoms (2j..2j+3) mod a_next.
__device__ __forceinline__ uint64_t spread_pairs(uint64_t mask, int a_next) {
  uint64_t s = mask;
  s = (s | (s << 16)) & 0x0000FFFF0000FFFFull;
  s = (s | (s << 8))  & 0x00FF00FF00FF00FFull;
  s = (s | (s << 4))  & 0x0F0F0F0F0F0F0F0Full;
  s = (s | (s << 2))  & 0x3333333333333333ull;
  s = (s | (s << 1))  & 0x5555555555555555ull;
  uint64_t pair = s | (s << 1);
  uint64_t lim = (a_next >= 64) ? ~0ull : ((1ull << a_next) - 1ull);
  uint64_t rot = ((pair << 2) | (pair >> (a_next - 2))) & lim;
  return (pair | rot) & lim;
}

// Bitonic sort (descending) of 16 uint32 in registers; fully unrolled, static
// indices, pure v_min_u32/v_max_u32.
__device__ __forceinline__ void bsort16(uint32_t (&v)[16]) {
#pragma unroll
  for (int sz = 2; sz <= 16; sz <<= 1) {
#pragma unroll
    for (int st = sz >> 1; st > 0; st >>= 1) {
#pragma unroll
      for (int i = 0; i < 16; ++i) {
        int l = i ^ st;
        if (l > i) {
          uint32_t a = v[i], c = v[l];
          uint32_t mx = a > c ? a : c;
          uint32_t mn = a > c ? c : a;
          bool desc = ((i & sz) == 0);
          v[i] = desc ? mx : mn;
          v[l] = desc ? mn : mx;
        }
      }
    }
  }
}

__device__ __forceinline__ void bmerge16(uint32_t (&v)[16]) {
#pragma unroll
  for (int st = 8; st > 0; st >>= 1) {
#pragma unroll
    for (int i = 0; i < 16; ++i) {
      int l = i ^ st;
      if (l > i) {
        uint32_t a = v[i], c = v[l];
        v[i] = a > c ? a : c;
        v[l] = a > c ? c : a;
      }
    }
  }
}

// Conv numerics (validated): per atom, single f32 accumulator from 0,
// sequential __fmaf_rn in (ky,kx,c) step order, bias added last as a separate
// __fadd_rn. Selection: jax top_k semantics — exactly K kept, boundary ties
// broken toward LOWEST channel index. run[] = sorted top-16 multiset of |act|
// (padding zeros can't displace real top-K since K <= N); m = run[K-1] is the
// K-th largest with multiplicity; quota = #{i<K: run[i]==m} == K - #{|a|>m}.
__global__ __launch_bounds__(256, 4)
void hrtk_main(const float* __restrict__ x, float* __restrict__ out) {
  __shared__ float smem[256 * 27];
  int p = blockIdx.x * blockDim.x + threadIdx.x;
  if (p >= PIX) return;
  int bi = p / PLANE;
  int r  = p % PLANE;
  int h  = r / WOUT;
  int wc = r % WOUT;

  // Stage the 3x3x3 patch into LDS in step order s = ky*9+kx*3+c (value from
  // source (c,ky,kx)) — matches g_wPad's step enumeration exactly.
  // Per-thread row, stride 27 words -> 2 lanes/bank (free per m136).
  float* pxl = &smem[threadIdx.x * 27];
  const float* xb = x + (size_t)bi * 3 * HIN * WIN;
#pragma unroll
  for (int ky = 0; ky < 3; ++ky)
#pragma unroll
    for (int kx = 0; kx < 3; ++kx)
#pragma unroll
      for (int c = 0; c < 3; ++c)
        pxl[ky * 9 + kx * 3 + c] =
            xb[c * HIN * WIN + (size_t)(h + ky) * WIN + (wc + kx)];

  size_t outp = (size_t)bi * 120 * PLANE + (size_t)h * WOUT + wc;
  uint64_t allow = ~0ull;   // level 0 ungated

#pragma unroll 1
  for (int lvl = 0; lvl < 4; ++lvl) {
    const int N = cN[lvl], K = cK[lvl], ch0 = cCH0[lvl];
    const float* wL = g_wPad + lvl * 27 * 64;
    const float* bL = g_bPad + lvl * 64;

    float act[64];
#pragma unroll
    for (int q = 0; q < 4; ++q)
      if (q * 16 < N) {
#pragma unroll
        for (int i = 0; i < 16; ++i) act[q * 16 + i] = 0.0f;
      }

    // ---- conv: s rolled (27), quarters unrolled+guarded ----
    float pcur = pxl[0];
#pragma unroll 1
    for (int s = 0; s < 27; ++s) {
      const float* wrow = wL + s * 64;                 // uniform -> s_load
      float pn = pxl[(s + 1 == 27) ? 0 : (s + 1)];     // prefetch next px
#pragma unroll
      for (int q = 0; q < 4; ++q)
        if (q * 16 < N) {
#pragma unroll
          for (int i = 0; i < 16; ++i)
            act[q * 16 + i] = __fmaf_rn(pcur, wrow[q * 16 + i], act[q * 16 + i]);
        }
      pcur = pn;
    }

    // ---- bias + gate ----
#pragma unroll
    for (int q = 0; q < 4; ++q)
      if (q * 16 < N) {
#pragma unroll
        for (int i = 0; i < 16; ++i) {
          int j = q * 16 + i;
          float a = __fadd_rn(act[j], bL[j]);          // bias after conv
          act[j] = ((allow >> j) & 1ull) ? a : 0.0f;
        }
      }

    // ---- selection: sorted top-16 via grouped bitonic ----
    uint32_t run[16];
#pragma unroll
    for (int i = 0; i < 16; ++i)
      run[i] = __float_as_uint(act[i]) & 0x7fffffffu;
    bsort16(run);
#pragma unroll
    for (int g = 1; g < 4; ++g) {
      if (g * 16 < N) {
        uint32_t tmp[16];
#pragma unroll
        for (int i = 0; i < 16; ++i)
          tmp[i] = __float_as_uint(act[g * 16 + i]) & 0x7fffffffu;
        bsort16(tmp);
#pragma unroll
        for (int i = 0; i < 16; ++i) {   // keep top-16 of the two desc runs
          uint32_t c = tmp[15 - i];
          run[i] = run[i] > c ? run[i] : c;
        }
        bmerge16(run);                   // re-sort (run stays fully sorted)
      }
    }

    uint32_t mb = 0;                     // m = run[K-1], K runtime uniform
#pragma unroll
    for (int i = 0; i < 16; ++i) mb = (i == K - 1) ? run[i] : mb;
    float m = __uint_as_float(mb);
    int quota = 0;                       // #{i<K: run[i]==m}
#pragma unroll
    for (int i = 0; i < 16; ++i) quota += (i < K && run[i] == mb) ? 1 : 0;

    // ---- keep + store + mask ----
    uint64_t msk = 0;
    float* outL = out + outp + (size_t)ch0 * PLANE;
#pragma unroll
    for (int q = 0; q < 4; ++q)
      if (q * 16 < N) {
#pragma unroll
        for (int i = 0; i < 16; ++i) {
          int j = q * 16 + i;
          if (j < N) {                   // uniform guard (N=8 case in q0)
            float aj = fabsf(act[j]);
            bool eq = (aj == m);
            bool keep = (aj > m) || (eq && quota > 0);
            quota -= eq ? 1 : 0;
            float v = keep ? act[j] : 0.0f;
            outL[(size_t)j * PLANE] = v;
            msk |= (v != 0.0f) ? (1ull << j) : 0ull;
          }
        }
      }

    if (lvl < 3) allow = spread_pairs(msk, cN[lvl + 1]);
  }
}

extern "C" void kernel_launch(void* const* d_in, const int* in_sizes, int n_in,
                              void* d_out, int out_size, void* d_ws, size_t ws_size,
                              hipStream_t stream) {
  const float* x = (const float*)d_in[0];
  const float* w = (const float*)d_in[1];
  const float* b = (const float*)d_in[2];
  float* out = (float*)d_out;

  wprep<<<dim3((4 * 27 * 64 + 255) / 256), dim3(256), 0, stream>>>(w, b);
  dim3 blk(256), grid((PIX + 255) / 256);
  hrtk_main<<<grid, blk, 0, stream>>>(x, out);
}

// Round 6
// 307.342 us; speedup vs baseline: 1.1505x; 1.1505x over previous
//
#include <hip/hip_runtime.h>
#include <stdint.h>

static constexpr int HIN = 256, WIN = 256, HO = 254, WOUT = 254, NB = 8;
static constexpr int PLANE = HO * WOUT;       // 64516
static constexpr int PIX = NB * PLANE;        // 516128

// Per-level atom counts N = {8,16,32,64}, K = {2,4,8,16}, ch0 = {0,8,24,56}.
// Unified tables padded to 64 atoms/level (zeros beyond N): one rolled level
// loop => the whole kernel body is emitted ONCE (~20 KB) and stays I-cache
// resident. Padded atoms compute exactly 0.0f; their stores land on
// higher-level channels that this same thread overwrites later (harmless).
__device__ float g_wPad[4 * 27 * 64];
__device__ float g_bPad[4 * 64];

__constant__ int cN[4]   = {8, 16, 32, 64};
__constant__ int cK[4]   = {2, 4, 8, 16};
__constant__ int cCH0[4] = {0, 8, 24, 56};

// g_wPad[L][s][j] = w[(ch0_L+j)*27 + t(s)] for j<N_L else 0, where step
// s = ky*9+kx*3+c enumerates the VALIDATED (ky,kx,c) FMA order and
// t(s) = c*9+ky*3+kx is the source (c,ky,kx) layout offset.
__global__ void wprep(const float* __restrict__ w, const float* __restrict__ b) {
  int i = blockIdx.x * blockDim.x + threadIdx.x;
  if (i < 4 * 64) {
    int L = i / 64, j = i % 64;
    int N = 8 << L;
    int ch0 = (L == 0) ? 0 : (L == 1) ? 8 : (L == 2) ? 24 : 56;
    g_bPad[i] = (j < N) ? b[ch0 + j] : 0.0f;
  }
  if (i >= 4 * 27 * 64) return;
  int L = i / (27 * 64), r = i % (27 * 64), s = r / 64, j = r % 64;
  int N = 8 << L;
  int ch0 = (L == 0) ? 0 : (L == 1) ? 8 : (L == 2) ? 24 : 56;
  int ky = s / 9, kx = (s / 3) % 3, c = s % 3;
  g_wPad[i] = (j < N) ? w[(size_t)(ch0 + j) * 27 + c * 9 + ky * 3 + kx] : 0.0f;
}

// Ring connectivity: prev atom j feeds next atoms (2j..2j+3) mod a_next.
__device__ __forceinline__ uint64_t spread_pairs(uint64_t mask, int a_next) {
  uint64_t s = mask;
  s = (s | (s << 16)) & 0x0000FFFF0000FFFFull;
  s = (s | (s << 8))  & 0x00FF00FF00FF00FFull;
  s = (s | (s << 4))  & 0x0F0F0F0F0F0F0F0Full;
  s = (s | (s << 2))  & 0x3333333333333333ull;
  s = (s | (s << 1))  & 0x5555555555555555ull;
  uint64_t pair = s | (s << 1);
  uint64_t lim = (a_next >= 64) ? ~0ull : ((1ull << a_next) - 1ull);
  uint64_t rot = ((pair << 2) | (pair >> (a_next - 2))) & lim;
  return (pair | rot) & lim;
}

// Bitonic sort (descending) of 16 uint32 in registers; fully unrolled, static
// indices, pure v_min_u32/v_max_u32.
__device__ __forceinline__ void bsort16(uint32_t (&v)[16]) {
#pragma unroll
  for (int sz = 2; sz <= 16; sz <<= 1) {
#pragma unroll
    for (int st = sz >> 1; st > 0; st >>= 1) {
#pragma unroll
      for (int i = 0; i < 16; ++i) {
        int l = i ^ st;
        if (l > i) {
          uint32_t a = v[i], c = v[l];
          uint32_t mx = a > c ? a : c;
          uint32_t mn = a > c ? c : a;
          bool desc = ((i & sz) == 0);
          v[i] = desc ? mx : mn;
          v[l] = desc ? mn : mx;
        }
      }
    }
  }
}

__device__ __forceinline__ void bmerge16(uint32_t (&v)[16]) {
#pragma unroll
  for (int st = 8; st > 0; st >>= 1) {
#pragma unroll
    for (int i = 0; i < 16; ++i) {
      int l = i ^ st;
      if (l > i) {
        uint32_t a = v[i], c = v[l];
        v[i] = a > c ? a : c;
        v[l] = a > c ? c : a;
      }
    }
  }
}

// Conv numerics (validated): per atom, single f32 accumulator from 0,
// sequential __fmaf_rn in (ky,kx,c) step order (g3*9+ss ascending == the same
// chain), bias added last as a separate __fadd_rn. Selection: jax top_k
// semantics — exactly K kept, boundary ties broken toward LOWEST channel
// index; run[] = sorted top-16 multiset of |act|, m = run[K-1], quota =
// #{i<K: run[i]==m}. Padded atoms (act==0) can only consume quota AFTER all
// real atoms and only when m==0; their stores hit later-level channels that
// this thread overwrites afterward — harmless, so no per-element guard.
__global__ __launch_bounds__(128, 4)
void hrtk_main(const float* __restrict__ x, float* __restrict__ out) {
  __shared__ float smem[128 * 27];   // 13824 B/block -> 11 blocks/CU LDS-limit
  int p = blockIdx.x * blockDim.x + threadIdx.x;
  if (p >= PIX) return;
  int bi = p / PLANE;
  int r  = p % PLANE;
  int h  = r / WOUT;
  int wc = r % WOUT;

  // Stage the 3x3x3 patch into LDS in step order s = ky*9+kx*3+c (value from
  // source (c,ky,kx)) — matches g_wPad's step enumeration exactly.
  // Per-thread row, stride 27 words (odd) -> exactly 2 lanes/bank (free).
  float* pxl = &smem[threadIdx.x * 27];
  const float* xb = x + (size_t)bi * 3 * HIN * WIN;
#pragma unroll
  for (int ky = 0; ky < 3; ++ky)
#pragma unroll
    for (int kx = 0; kx < 3; ++kx)
#pragma unroll
      for (int c = 0; c < 3; ++c)
        pxl[ky * 9 + kx * 3 + c] =
            xb[c * HIN * WIN + (size_t)(h + ky) * WIN + (wc + kx)];

  size_t outp = (size_t)bi * 120 * PLANE + (size_t)h * WOUT + wc;
  uint64_t allow = ~0ull;   // level 0 ungated

#pragma unroll 1
  for (int lvl = 0; lvl < 4; ++lvl) {
    const int N = cN[lvl], K = cK[lvl], ch0 = cCH0[lvl];
    const float* wL = g_wPad + lvl * 27 * 64;
    const float* bL = g_bPad + lvl * 64;

    float act[64];
#pragma unroll
    for (int q = 0; q < 4; ++q)
      if (q * 16 < N) {
#pragma unroll
        for (int i = 0; i < 16; ++i) act[q * 16 + i] = 0.0f;
      }

    // ---- conv: 3 rolled s-groups of 9; pw[9] batch-read (deep ds prefetch),
    // quarter guards hoisted (12 evals/level), 9x16 FMA blocks unrolled ----
#pragma unroll 1
    for (int g3 = 0; g3 < 3; ++g3) {
      const float* pg = pxl + g3 * 9;
      float pw[9];
#pragma unroll
      for (int ss = 0; ss < 9; ++ss) pw[ss] = pg[ss];
      const float* wg = wL + g3 * 9 * 64;               // uniform -> s_load
#pragma unroll
      for (int q = 0; q < 4; ++q)
        if (q * 16 < N) {
#pragma unroll
          for (int ss = 0; ss < 9; ++ss) {
            const float* wr = wg + ss * 64 + q * 16;
#pragma unroll
            for (int i = 0; i < 16; ++i)
              act[q * 16 + i] = __fmaf_rn(pw[ss], wr[i], act[q * 16 + i]);
          }
        }
    }

    // ---- bias + gate ----
#pragma unroll
    for (int q = 0; q < 4; ++q)
      if (q * 16 < N) {
#pragma unroll
        for (int i = 0; i < 16; ++i) {
          int j = q * 16 + i;
          float a = __fadd_rn(act[j], bL[j]);          // bias after conv
          act[j] = ((allow >> j) & 1ull) ? a : 0.0f;
        }
      }

    // ---- selection: sorted top-16 via grouped bitonic ----
    uint32_t run[16];
#pragma unroll
    for (int i = 0; i < 16; ++i)
      run[i] = __float_as_uint(act[i]) & 0x7fffffffu;
    bsort16(run);
#pragma unroll
    for (int g = 1; g < 4; ++g) {
      if (g * 16 < N) {
        uint32_t tmp[16];
#pragma unroll
        for (int i = 0; i < 16; ++i)
          tmp[i] = __float_as_uint(act[g * 16 + i]) & 0x7fffffffu;
        bsort16(tmp);
#pragma unroll
        for (int i = 0; i < 16; ++i) {   // keep top-16 of the two desc runs
          uint32_t c = tmp[15 - i];
          run[i] = run[i] > c ? run[i] : c;
        }
        bmerge16(run);                   // re-sort (run stays fully sorted)
      }
    }

    uint32_t mb = 0;                     // m = run[K-1], K runtime uniform
#pragma unroll
    for (int i = 0; i < 16; ++i) mb = (i == K - 1) ? run[i] : mb;
    float m = __uint_as_float(mb);
    int quota = 0;                       // #{i<K: run[i]==m}
#pragma unroll
    for (int i = 0; i < 16; ++i) quota += (i < K && run[i] == mb) ? 1 : 0;

    // ---- keep + store + mask (quarter-guarded; padded j harmless) ----
    uint64_t msk = 0;
    float* outL = out + outp + (size_t)ch0 * PLANE;
#pragma unroll
    for (int q = 0; q < 4; ++q)
      if (q * 16 < N) {
#pragma unroll
        for (int i = 0; i < 16; ++i) {
          int j = q * 16 + i;
          float aj = fabsf(act[j]);
          bool eq = (aj == m);
          bool keep = (aj > m) || (eq && quota > 0);
          quota -= eq ? 1 : 0;
          float v = keep ? act[j] : 0.0f;
          outL[(size_t)j * PLANE] = v;
          msk |= (v != 0.0f) ? (1ull << j) : 0ull;
        }
      }

    if (lvl < 3) allow = spread_pairs(msk, cN[lvl + 1]);
  }
}

extern "C" void kernel_launch(void* const* d_in, const int* in_sizes, int n_in,
                              void* d_out, int out_size, void* d_ws, size_t ws_size,
                              hipStream_t stream) {
  const float* x = (const float*)d_in[0];
  const float* w = (const float*)d_in[1];
  const float* b = (const float*)d_in[2];
  float* out = (float*)d_out;

  wprep<<<dim3((4 * 27 * 64 + 255) / 256), dim3(256), 0, stream>>>(w, b);
  dim3 blk(128), grid((PIX + 127) / 128);
  hrtk_main<<<grid, blk, 0, stream>>>(x, out);
}

// Round 7
// 306.942 us; speedup vs baseline: 1.1520x; 1.0013x over previous
//
#include <hip/hip_runtime.h>
#include <stdint.h>

static constexpr int HIN = 256, WIN = 256, HO = 254, WOUT = 254, NB = 8;
static constexpr int PLANE = HO * WOUT;       // 64516
static constexpr int PIX = NB * PLANE;        // 516128

typedef float f32x4 __attribute__((ext_vector_type(4)));

// Per-level atom counts N = {8,16,32,64}, K = {2,4,8,16}, ch0 = {0,8,24,56}.
// Unified tables padded to 64 atoms/level (zeros beyond N): one rolled level
// loop => the whole kernel body is emitted ONCE and stays I-cache resident.
// Padded atoms compute exactly 0.0f; their stores land on higher-level
// channels that this same thread overwrites later (harmless).
// 16B-aligned so weight rows can be read as f32x4 per-lane global loads
// (identical address across lanes -> L1 broadcast; 27.6 KB is L1-resident).
__device__ __align__(16) float g_wPad[4 * 27 * 64];
__device__ float g_bPad[4 * 64];

__constant__ int cN[4]   = {8, 16, 32, 64};
__constant__ int cK[4]   = {2, 4, 8, 16};
__constant__ int cCH0[4] = {0, 8, 24, 56};

// g_wPad[L][s][j] = w[(ch0_L+j)*27 + t(s)] for j<N_L else 0, where step
// s = ky*9+kx*3+c enumerates the VALIDATED (ky,kx,c) FMA order and
// t(s) = c*9+ky*3+kx is the source (c,ky,kx) layout offset.
__global__ void wprep(const float* __restrict__ w, const float* __restrict__ b) {
  int i = blockIdx.x * blockDim.x + threadIdx.x;
  if (i < 4 * 64) {
    int L = i / 64, j = i % 64;
    int N = 8 << L;
    int ch0 = (L == 0) ? 0 : (L == 1) ? 8 : (L == 2) ? 24 : 56;
    g_bPad[i] = (j < N) ? b[ch0 + j] : 0.0f;
  }
  if (i >= 4 * 27 * 64) return;
  int L = i / (27 * 64), r = i % (27 * 64), s = r / 64, j = r % 64;
  int N = 8 << L;
  int ch0 = (L == 0) ? 0 : (L == 1) ? 8 : (L == 2) ? 24 : 56;
  int ky = s / 9, kx = (s / 3) % 3, c = s % 3;
  g_wPad[i] = (j < N) ? w[(size_t)(ch0 + j) * 27 + c * 9 + ky * 3 + kx] : 0.0f;
}

// Ring connectivity: prev atom j feeds next atoms (2j..2j+3) mod a_next.
__device__ __forceinline__ uint64_t spread_pairs(uint64_t mask, int a_next) {
  uint64_t s = mask;
  s = (s | (s << 16)) & 0x0000FFFF0000FFFFull;
  s = (s | (s << 8))  & 0x00FF00FF00FF00FFull;
  s = (s | (s << 4))  & 0x0F0F0F0F0F0F0F0Full;
  s = (s | (s << 2))  & 0x3333333333333333ull;
  s = (s | (s << 1))  & 0x5555555555555555ull;
  uint64_t pair = s | (s << 1);
  uint64_t lim = (a_next >= 64) ? ~0ull : ((1ull << a_next) - 1ull);
  uint64_t rot = ((pair << 2) | (pair >> (a_next - 2))) & lim;
  return (pair | rot) & lim;
}

// Bitonic sort (descending) of 16 uint32 in registers; fully unrolled, static
// indices, pure v_min_u32/v_max_u32.
__device__ __forceinline__ void bsort16(uint32_t (&v)[16]) {
#pragma unroll
  for (int sz = 2; sz <= 16; sz <<= 1) {
#pragma unroll
    for (int st = sz >> 1; st > 0; st >>= 1) {
#pragma unroll
      for (int i = 0; i < 16; ++i) {
        int l = i ^ st;
        if (l > i) {
          uint32_t a = v[i], c = v[l];
          uint32_t mx = a > c ? a : c;
          uint32_t mn = a > c ? c : a;
          bool desc = ((i & sz) == 0);
          v[i] = desc ? mx : mn;
          v[l] = desc ? mn : mx;
        }
      }
    }
  }
}

__device__ __forceinline__ void bmerge16(uint32_t (&v)[16]) {
#pragma unroll
  for (int st = 8; st > 0; st >>= 1) {
#pragma unroll
    for (int i = 0; i < 16; ++i) {
      int l = i ^ st;
      if (l > i) {
        uint32_t a = v[i], c = v[l];
        v[i] = a > c ? a : c;
        v[l] = a > c ? c : a;
      }
    }
  }
}

// Conv numerics (validated): per atom, single f32 accumulator from 0,
// sequential __fmaf_rn in (ky,kx,c) step order (g3*9+ss ascending == the same
// chain), bias added last as a separate __fadd_rn. Selection: jax top_k
// semantics — exactly K kept, boundary ties broken toward LOWEST channel
// index; run[] = sorted top-16 multiset of |act|, m = run[K-1], quota =
// #{i<K: run[i]==m}. Padded atoms (act==0) can only consume quota AFTER all
// real atoms and only when m==0; their stores hit later-level channels that
// this thread overwrites afterward — harmless, so no per-element guard.
__global__ __launch_bounds__(128, 4)
void hrtk_main(const float* __restrict__ x, float* __restrict__ out) {
  __shared__ float smem[128 * 27];   // 13824 B/block -> 11 blocks/CU LDS-limit
  int p = blockIdx.x * blockDim.x + threadIdx.x;
  if (p >= PIX) return;
  int bi = p / PLANE;
  int r  = p % PLANE;
  int h  = r / WOUT;
  int wc = r % WOUT;

  // Stage the 3x3x3 patch into LDS in step order s = ky*9+kx*3+c (value from
  // source (c,ky,kx)) — matches g_wPad's step enumeration exactly.
  // Per-thread row, stride 27 words (odd) -> exactly 2 lanes/bank (free).
  float* pxl = &smem[threadIdx.x * 27];
  const float* xb = x + (size_t)bi * 3 * HIN * WIN;
#pragma unroll
  for (int ky = 0; ky < 3; ++ky)
#pragma unroll
    for (int kx = 0; kx < 3; ++kx)
#pragma unroll
      for (int c = 0; c < 3; ++c)
        pxl[ky * 9 + kx * 3 + c] =
            xb[c * HIN * WIN + (size_t)(h + ky) * WIN + (wc + kx)];

  // Per-thread 32-bit BYTE offset within out; per-channel base is uniform ->
  // global_store saddr form (SGPR base + 32-bit voffset), no per-store VALU.
  uint32_t tofs4 = (uint32_t)(bi * 120 * PLANE + r) * 4u;
  char* outB = (char*)out;
  uint64_t allow = ~0ull;   // level 0 ungated

#pragma unroll 1
  for (int lvl = 0; lvl < 4; ++lvl) {
    const int N = cN[lvl], K = cK[lvl], ch0 = cCH0[lvl];
    const float* wL = g_wPad + lvl * 27 * 64;
    const float* bL = g_bPad + lvl * 64;

    float act[64];
#pragma unroll
    for (int q = 0; q < 4; ++q)
      if (q * 16 < N) {
#pragma unroll
        for (int i = 0; i < 16; ++i) act[q * 16 + i] = 0.0f;
      }

    // ---- conv: 3 rolled s-groups of 9; pw[9] batch-read from LDS (deep ds
    // prefetch); weights as per-lane f32x4 GLOBAL loads (L1-broadcast, deep
    // vmcnt pipelining — replaces the s_load/lgkmcnt serialization) ----
#pragma unroll 1
    for (int g3 = 0; g3 < 3; ++g3) {
      const float* pg = pxl + g3 * 9;
      float pw[9];
#pragma unroll
      for (int ss = 0; ss < 9; ++ss) pw[ss] = pg[ss];
      const float* wg = wL + g3 * 9 * 64;
#pragma unroll
      for (int q = 0; q < 4; ++q)
        if (q * 16 < N) {
#pragma unroll
          for (int ss = 0; ss < 9; ++ss) {
            const f32x4* wr = (const f32x4*)(wg + ss * 64 + q * 16);
            f32x4 w0 = wr[0], w1 = wr[1], w2 = wr[2], w3 = wr[3];
#pragma unroll
            for (int i = 0; i < 4; ++i) {
              act[q * 16 + 0  + i] = __fmaf_rn(pw[ss], w0[i], act[q * 16 + 0  + i]);
              act[q * 16 + 4  + i] = __fmaf_rn(pw[ss], w1[i], act[q * 16 + 4  + i]);
              act[q * 16 + 8  + i] = __fmaf_rn(pw[ss], w2[i], act[q * 16 + 8  + i]);
              act[q * 16 + 12 + i] = __fmaf_rn(pw[ss], w3[i], act[q * 16 + 12 + i]);
            }
          }
        }
    }

    // ---- bias + gate ----
#pragma unroll
    for (int q = 0; q < 4; ++q)
      if (q * 16 < N) {
#pragma unroll
        for (int i = 0; i < 16; ++i) {
          int j = q * 16 + i;
          float a = __fadd_rn(act[j], bL[j]);          // bias after conv
          act[j] = ((allow >> j) & 1ull) ? a : 0.0f;
        }
      }

    // ---- selection: sorted top-16 via grouped bitonic ----
    uint32_t run[16];
#pragma unroll
    for (int i = 0; i < 16; ++i)
      run[i] = __float_as_uint(act[i]) & 0x7fffffffu;
    bsort16(run);
#pragma unroll
    for (int g = 1; g < 4; ++g) {
      if (g * 16 < N) {
        uint32_t tmp[16];
#pragma unroll
        for (int i = 0; i < 16; ++i)
          tmp[i] = __float_as_uint(act[g * 16 + i]) & 0x7fffffffu;
        bsort16(tmp);
#pragma unroll
        for (int i = 0; i < 16; ++i) {   // keep top-16 of the two desc runs
          uint32_t c = tmp[15 - i];
          run[i] = run[i] > c ? run[i] : c;
        }
        bmerge16(run);                   // re-sort (run stays fully sorted)
      }
    }

    uint32_t mb = 0;                     // m = run[K-1], K runtime uniform
#pragma unroll
    for (int i = 0; i < 16; ++i) mb = (i == K - 1) ? run[i] : mb;
    float m = __uint_as_float(mb);
    int quota = 0;                       // #{i<K: run[i]==m}
#pragma unroll
    for (int i = 0; i < 16; ++i) quota += (i < K && run[i] == mb) ? 1 : 0;

    // ---- keep + store + mask (quarter-guarded; padded j harmless).
    // Store: uniform SGPR base per channel + tofs4 voffset (saddr form). ----
    uint64_t msk = 0;
#pragma unroll
    for (int q = 0; q < 4; ++q)
      if (q * 16 < N) {
#pragma unroll
        for (int i = 0; i < 16; ++i) {
          int j = q * 16 + i;
          float aj = fabsf(act[j]);
          bool eq = (aj == m);
          bool keep = (aj > m) || (eq && quota > 0);
          quota -= eq ? 1 : 0;
          float v = keep ? act[j] : 0.0f;
          *(float*)(outB + (size_t)(ch0 + j) * PLANE * 4 + tofs4) = v;
          msk |= (v != 0.0f) ? (1ull << j) : 0ull;
        }
      }

    if (lvl < 3) allow = spread_pairs(msk, cN[lvl + 1]);
  }
}

extern "C" void kernel_launch(void* const* d_in, const int* in_sizes, int n_in,
                              void* d_out, int out_size, void* d_ws, size_t ws_size,
                              hipStream_t stream) {
  const float* x = (const float*)d_in[0];
  const float* w = (const float*)d_in[1];
  const float* b = (const float*)d_in[2];
  float* out = (float*)d_out;

  wprep<<<dim3((4 * 27 * 64 + 255) / 256), dim3(256), 0, stream>>>(w, b);
  dim3 blk(128), grid((PIX + 127) / 128);
  hrtk_main<<<grid, blk, 0, stream>>>(x, out);
}